// Round 12
// baseline (235.050 us; speedup 1.0000x reference)
//
#include <hip/hip_runtime.h>
#include <math.h>

// LogicLayer: y[b,o] = prod_i ( a[b,i] + nw[o,i] - a[b,i]*nw[o,i] )
//   fw = sigmoid(W[o,i]) in (0,1); term = 1 - (1-a)*fw = fma(a-1, fw, 1).
// B=4096, OUT=256, IN=256, fp32.
//
// r12 == r11 (diagnosis round, never ran due to broker timeout).
// r10 passed at 91.6us total but the top-5 rocprof rows were all 41us
// harness fills — our mains (<41us each) were invisible. This round
// replicates the inner loop R x per dispatch (asm sinks prevent DCE,
// rule #17) so both variants exceed the fill threshold and surface with
// full counters:
//   S = r6-style forced-SMEM pipeline (s_load_dwordx4, all-asm lgkm), x12
//   P = r9 plain compiler path, x3  (runs last, owns d_out: pass guaranteed)
// Readout: per-rep dur = dur/REPS; VGPR_Count arbitrates register-pressure
// theory; VALUBusy/SQ_LDS_BANK_CONFLICT/FETCH arbitrate fw-not-scalarized
// vs swizzle-broken vs pk-half-rate.

#define IN_DIM 256
#define OUT_DIM 256
#define B_DIM 4096
#define BDIM 512
#define ROWS 64
#define LDS_STRIDE 258  // S-variant row stride (floats)

typedef float v2f __attribute__((ext_vector_type(2)));
typedef unsigned int u32x4 __attribute__((ext_vector_type(4)));

__device__ __forceinline__ v2f pk_fma(v2f a, v2f b, v2f c) {
#if __has_builtin(__builtin_elementwise_fma)
  return __builtin_elementwise_fma(a, b, c);  // llvm.fma.v2f32 -> v_pk_fma_f32
#else
  v2f r;
  r.x = fmaf(a.x, b.x, c.x);
  r.y = fmaf(a.y, b.y, c.y);
  return r;
#endif
}

__device__ __forceinline__ float sigmoidf_dev(float x) {
  if (x >= 0.0f) {
    return 1.0f / (1.0f + expf(-x));
  }
  const float e = expf(x);
  return e / (1.0f + e);
}

// ---- Kernel 1: fw[t] = sigmoid(W[t]) ---------------------------------------
__global__ __launch_bounds__(256) void sigmoid_ew(const float* __restrict__ w,
                                                  float* __restrict__ fw) {
  const int t = blockIdx.x * 256 + threadIdx.x;
  fw[t] = sigmoidf_dev(w[t]);
}

// ============================ Variant S (asm SMEM) ==========================
__device__ __forceinline__ void stage_am_pad(const float* __restrict__ atoms,
                                             int b0, int t, float* lds) {
#pragma unroll
  for (int rnd = 0; rnd < 8; ++rnd) {
    const int e = rnd * 2048 + t * 4;
    const float4 v =
        *reinterpret_cast<const float4*>(atoms + (size_t)b0 * IN_DIM + e);
    const int row = e >> 8;
    const int col = e & 255;
    float* dst = &lds[row * LDS_STRIDE + col];
    v2f p0, p1;
    p0.x = v.x - 1.0f; p0.y = v.y - 1.0f;
    p1.x = v.z - 1.0f; p1.y = v.w - 1.0f;
    *reinterpret_cast<v2f*>(dst) = p0;
    *reinterpret_cast<v2f*>(dst + 2) = p1;
  }
}

#define ISSUE(P, ADDR)                                                      \
  do {                                                                      \
    const unsigned long long _fa = (unsigned long long)(ADDR);              \
    asm volatile(                                                           \
        "s_load_dwordx4 %0, %8, 0x0\n\t"                                    \
        "s_load_dwordx4 %1, %8, 0x400\n\t"                                  \
        "s_load_dwordx4 %2, %8, 0x800\n\t"                                  \
        "s_load_dwordx4 %3, %8, 0xc00\n\t"                                  \
        "s_load_dwordx4 %4, %8, 0x1000\n\t"                                 \
        "s_load_dwordx4 %5, %8, 0x1400\n\t"                                 \
        "s_load_dwordx4 %6, %8, 0x1800\n\t"                                 \
        "s_load_dwordx4 %7, %8, 0x1c00"                                     \
        : "=&s"(P##0), "=&s"(P##1), "=&s"(P##2), "=&s"(P##3), "=&s"(P##4),  \
          "=&s"(P##5), "=&s"(P##6), "=&s"(P##7)                             \
        : "s"(_fa));                                                        \
  } while (0)

#define DSREAD(AM01, AM23, ADDRB)                                           \
  asm volatile("ds_read_b64 %0, %2\n\t"                                     \
               "ds_read_b64 %1, %2 offset:8"                                \
               : "=&v"(AM01), "=&v"(AM23)                                   \
               : "v"(ADDRB))

#define WAITLGKM()                                    \
  do {                                                \
    asm volatile("s_waitcnt lgkmcnt(0)");             \
    __builtin_amdgcn_sched_barrier(0);                \
  } while (0)

#define CONSUME(P, AM01, AM23)                                   \
  do {                                                           \
    _Pragma("unroll") for (int j = 0; j < 8; ++j) {              \
      const u32x4 q = (j == 0) ? P##0                            \
                    : (j == 1) ? P##1                            \
                    : (j == 2) ? P##2                            \
                    : (j == 3) ? P##3                            \
                    : (j == 4) ? P##4                            \
                    : (j == 5) ? P##5                            \
                    : (j == 6) ? P##6 : P##7;                    \
      v2f f01, f23;                                              \
      f01.x = __uint_as_float(q[0]);                             \
      f01.y = __uint_as_float(q[1]);                             \
      f23.x = __uint_as_float(q[2]);                             \
      f23.y = __uint_as_float(q[3]);                             \
      const v2f t01 = pk_fma(AM01, f01, ones);                   \
      const v2f t23 = pk_fma(AM23, f23, ones);                   \
      prodv[j] *= t01 * t23;                                     \
    }                                                            \
  } while (0)

template <int REPS>
__global__ __launch_bounds__(BDIM) void logic_sload_rep(
    const float* __restrict__ atoms, const float* __restrict__ fw,
    float* __restrict__ out) {
  __shared__ float lds[ROWS * LDS_STRIDE];
  const int t = threadIdx.x;
  const int bb = blockIdx.x >> 2;  // 0..63
  const int ob = blockIdx.x & 3;   // 0..3
  const int b0 = bb * ROWS;

  stage_am_pad(atoms, b0, t, lds);
  __syncthreads();

  const int r = t & 63;
  const int w = __builtin_amdgcn_readfirstlane(t >> 6);
  const unsigned abase =
      (unsigned)(unsigned long long)(const void*)&lds[r * LDS_STRIDE];
  const float* __restrict__ frow = fw + (size_t)(ob * 64 + w * 8) * IN_DIM;

  const v2f ones = {1.0f, 1.0f};
  v2f prodv[8];

  u32x4 qa0, qa1, qa2, qa3, qa4, qa5, qa6, qa7;
  u32x4 qb0, qb1, qb2, qb3, qb4, qb5, qb6, qb7;
  v2f amA01, amA23, amB01, amB23;

#pragma unroll 1
  for (int rep = 0; rep < REPS; ++rep) {
#pragma unroll
    for (int j = 0; j < 8; ++j) prodv[j] = (v2f){1.0f, 1.0f};

    ISSUE(qa, frow);
    DSREAD(amA01, amA23, abase);

#pragma unroll 1
    for (int i = 0; i < IN_DIM; i += 8) {
      const int iB = (i + 4) & 255;
      const int iA2 = (i + 8) & 255;

      WAITLGKM();
      ISSUE(qb, frow + iB);
      DSREAD(amB01, amB23, abase + (unsigned)iB * 4u);
      CONSUME(qa, amA01, amA23);

      WAITLGKM();
      ISSUE(qa, frow + iA2);
      DSREAD(amA01, amA23, abase + (unsigned)iA2 * 4u);
      CONSUME(qb, amB01, amB23);
    }
    WAITLGKM();
    // sink: keep each rep's result observable (rule #17 — no DCE/merge)
#pragma unroll
    for (int j = 0; j < 8; ++j) asm volatile("" : "+v"(prodv[j]));
  }

  float* op = out + (size_t)(b0 + r) * OUT_DIM + ob * 64 + w * 8;
  float4 s0, s1;
  s0.x = prodv[0].x * prodv[0].y;
  s0.y = prodv[1].x * prodv[1].y;
  s0.z = prodv[2].x * prodv[2].y;
  s0.w = prodv[3].x * prodv[3].y;
  s1.x = prodv[4].x * prodv[4].y;
  s1.y = prodv[5].x * prodv[5].y;
  s1.z = prodv[6].x * prodv[6].y;
  s1.w = prodv[7].x * prodv[7].y;
  *reinterpret_cast<float4*>(op) = s0;
  *reinterpret_cast<float4*>(op + 4) = s1;
}

// ============================ Variant P (plain, r9) =========================
template <int NOJ_T, int OBLOCKS_T, int MINW, bool SIG, int REPS>
__global__ __launch_bounds__(BDIM, MINW) void logic_v_rep(
    const float* __restrict__ atoms, const float* __restrict__ fw,
    float* __restrict__ out) {
  __shared__ float lds[ROWS * IN_DIM];  // 64KB, XOR-swizzled 16B units

  const int t = threadIdx.x;
  const int idx = blockIdx.x;
  const int xcd = idx & 7;
  const int local = idx >> 3;
  const int bb = xcd + 8 * (local / OBLOCKS_T);
  const int ob = local % OBLOCKS_T;
  const int b0 = bb * ROWS;

  {
#pragma unroll
    for (int rnd = 0; rnd < 8; ++rnd) {
      const int e = rnd * 2048 + t * 4;
      const int row = e >> 8;
      const int lane_u = (e & 255) >> 2;
      const int su = lane_u ^ (row & 7);
      const float4 v =
          *reinterpret_cast<const float4*>(atoms + (size_t)b0 * IN_DIM + e);
      float4 p;
      p.x = v.x - 1.0f;
      p.y = v.y - 1.0f;
      p.z = v.z - 1.0f;
      p.w = v.w - 1.0f;
      *reinterpret_cast<float4*>(&lds[row * IN_DIM + (su << 2)]) = p;
    }
  }
  __syncthreads();

  const int r = t & 63;
  const int w = __builtin_amdgcn_readfirstlane(t >> 6);
  const int rm = r & 7;
  const float* rowbase = lds + r * IN_DIM;
  const int ocol0 = ob * (8 * NOJ_T) + w * NOJ_T;
  const float* __restrict__ frow = fw + (size_t)ocol0 * IN_DIM;

  const v2f ones = {1.0f, 1.0f};
  v2f prodv[NOJ_T];

#pragma unroll 1
  for (int rep = 0; rep < REPS; ++rep) {
#pragma unroll
    for (int j = 0; j < NOJ_T; ++j) prodv[j] = (v2f){1.0f, 1.0f};

#pragma unroll 4
    for (int i = 0; i < IN_DIM; i += 4) {
      const float4 am4 = *reinterpret_cast<const float4*>(
          rowbase + ((((i >> 2) ^ rm)) << 2));
      v2f am01, am23;
      am01.x = am4.x; am01.y = am4.y;
      am23.x = am4.z; am23.y = am4.w;
#pragma unroll
      for (int j = 0; j < NOJ_T; ++j) {
        float4 f4 = *reinterpret_cast<const float4*>(frow + j * IN_DIM + i);
        if (SIG) {
          f4.x = sigmoidf_dev(f4.x);
          f4.y = sigmoidf_dev(f4.y);
          f4.z = sigmoidf_dev(f4.z);
          f4.w = sigmoidf_dev(f4.w);
        }
        v2f f01, f23;
        f01.x = f4.x; f01.y = f4.y;
        f23.x = f4.z; f23.y = f4.w;
        const v2f t01 = pk_fma(am01, f01, ones);
        const v2f t23 = pk_fma(am23, f23, ones);
        prodv[j] *= t01 * t23;
      }
    }
    // sink (rule #17)
#pragma unroll
    for (int j = 0; j < NOJ_T; ++j) asm volatile("" : "+v"(prodv[j]));
  }

  float* op = out + (size_t)(b0 + r) * OUT_DIM + ocol0;
#pragma unroll
  for (int j0 = 0; j0 < NOJ_T; j0 += 4) {
    float4 s;
    s.x = prodv[j0 + 0].x * prodv[j0 + 0].y;
    s.y = prodv[j0 + 1].x * prodv[j0 + 1].y;
    s.z = prodv[j0 + 2].x * prodv[j0 + 2].y;
    s.w = prodv[j0 + 3].x * prodv[j0 + 3].y;
    *reinterpret_cast<float4*>(op + j0) = s;
  }
}

extern "C" void kernel_launch(void* const* d_in, const int* in_sizes, int n_in,
                              void* d_out, int out_size, void* d_ws,
                              size_t ws_size, hipStream_t stream) {
  const float* atoms = (const float*)d_in[0];    // [4096, 256]
  const float* weights = (const float*)d_in[1];  // [256, 256]
  float* out = (float*)d_out;                    // [4096, 256]

  if (ws_size >= (size_t)OUT_DIM * IN_DIM * sizeof(float)) {
    float* fw = (float*)d_ws;
    sigmoid_ew<<<dim3((OUT_DIM * IN_DIM) / 256), dim3(256), 0, stream>>>(
        weights, fw);
    // S x12: forced-SMEM pipeline (diagnostic replicate -> top-5 visibility)
    logic_sload_rep<12><<<dim3(256), dim3(BDIM), 0, stream>>>(atoms, fw, out);
    // P x3: plain r9 config A; runs last, owns d_out (known-good path)
    logic_v_rep<8, 4, 2, false, 3><<<dim3(256), dim3(BDIM), 0, stream>>>(
        atoms, fw, out);
  } else {
    logic_v_rep<4, 8, 4, true, 1><<<dim3(512), dim3(BDIM), 0, stream>>>(
        atoms, weights, out);
  }
}